// Round 11
// baseline (77.322 us; speedup 1.0000x reference)
//
#include <hip/hip_runtime.h>
#include <math.h>

typedef float v2f __attribute__((ext_vector_type(2)));

__device__ __forceinline__ v2f vfma(v2f a, v2f b, v2f c) {
  return __builtin_elementwise_fma(a, b, c);
}
__device__ __forceinline__ v2f vmax2(v2f a, v2f b) {
  return __builtin_elementwise_max(a, b);
}
__device__ __forceinline__ v2f s2(float x) { return (v2f){x, x}; }

namespace {
constexpr int kB  = 2048;
constexpr int kSW = 2048;      // short width
constexpr int kLW = 8192;      // long width
constexpr int kLP = kLW / 2;   // pooled length = 4096
constexpr int kLR = 16;        // batch rows per long block (8 packed pairs)
constexpr int kSR = 8;         // batch rows per short block (4 packed pairs)
constexpr int kLSL = 16;       // long slices (256 pooled positions each)
constexpr int kSSL = 4;        // short slices (512 positions each)
constexpr int kLBLK = kLSL * (kB / kLR);   // 2048
constexpr int kSBLK = kSSL * (kB / kSR);   // 1024
constexpr int kNBLK = kLBLK + kSBLK;       // 3072
}

// ------------- long: conv(k=5,p=2) -> relu -> maxpool(2) -> partial dot -------------
// 256 threads = 256 pooled positions; rows processed in packed fp32 pairs.
__device__ __forceinline__ void long_path(
    int sl, int rg, const float* __restrict__ xl, const float* __restrict__ cw,
    const float* __restrict__ cb, const float* __restrict__ lw,
    float* __restrict__ partL, float (*red)[32]) {
  const int t = threadIdx.x;
  const int b0 = rg * kLR;
  const int P = sl * 256 + t;          // global pooled position

  float wgt[8][5], bias[8];
#pragma unroll
  for (int c = 0; c < 8; ++c) {
#pragma unroll
    for (int k = 0; k < 5; ++k) wgt[c][k] = cw[c * 5 + k];
    bias[c] = cb[c];
  }

  float la[8], lb[8];                  // lw fragments, held for block lifetime
#pragma unroll
  for (int c = 0; c < 8; ++c) {
    la[c] = lw[(size_t)c * kLP + P];
    lb[c] = lw[(size_t)(8 + c) * kLP + P];
  }

  v2f acc0[kLR / 2], acc1[kLR / 2];
#pragma unroll
  for (int p = 0; p < kLR / 2; ++p) { acc0[p] = s2(0.f); acc1[p] = s2(0.f); }

  const bool lo = (P > 0);
  const bool hi = (P < kLP - 1);
  const float* xb = xl + (size_t)b0 * kLW + 2 * P;

#pragma unroll
  for (int p = 0; p < kLR / 2; ++p) {
    const float* x0 = xb + (size_t)(2 * p) * kLW;
    const float* x1 = xb + (size_t)(2 * p + 1) * kLW;
    float2 A0 = lo ? *reinterpret_cast<const float2*>(x0 - 2) : make_float2(0.f, 0.f);
    float2 A1 = lo ? *reinterpret_cast<const float2*>(x1 - 2) : make_float2(0.f, 0.f);
    float2 B0 = *reinterpret_cast<const float2*>(x0);
    float2 B1 = *reinterpret_cast<const float2*>(x1);
    float2 C0 = hi ? *reinterpret_cast<const float2*>(x0 + 2) : make_float2(0.f, 0.f);
    float2 C1 = hi ? *reinterpret_cast<const float2*>(x1 + 2) : make_float2(0.f, 0.f);
    // packed windows: lane = batch row (lo = row 2p, hi = row 2p+1)
    const v2f W0 = {A0.x, A1.x}, W1 = {A0.y, A1.y};
    const v2f W2 = {B0.x, B1.x}, W3 = {B0.y, B1.y};
    const v2f W4 = {C0.x, C1.x}, W5 = {C0.y, C1.y};
#pragma unroll
    for (int c = 0; c < 8; ++c) {
      v2f v0 = vfma(s2(wgt[c][0]), W0,
               vfma(s2(wgt[c][1]), W1,
               vfma(s2(wgt[c][2]), W2,
               vfma(s2(wgt[c][3]), W3,
               vfma(s2(wgt[c][4]), W4, s2(bias[c]))))));
      v2f v1 = vfma(s2(wgt[c][0]), W1,
               vfma(s2(wgt[c][1]), W2,
               vfma(s2(wgt[c][2]), W3,
               vfma(s2(wgt[c][3]), W4,
               vfma(s2(wgt[c][4]), W5, s2(bias[c]))))));
      const v2f m = vmax2(vmax2(v0, v1), s2(0.f));
      acc0[p] = vfma(m, s2(la[c]), acc0[p]);
      acc1[p] = vfma(m, s2(lb[c]), acc1[p]);
    }
  }

  // one reduction per block: in-wave butterfly, then cross-wave via LDS
#pragma unroll
  for (int m = 1; m < 64; m <<= 1) {
#pragma unroll
    for (int p = 0; p < kLR / 2; ++p) {
      acc0[p].x += __shfl_xor(acc0[p].x, m);
      acc0[p].y += __shfl_xor(acc0[p].y, m);
      acc1[p].x += __shfl_xor(acc1[p].x, m);
      acc1[p].y += __shfl_xor(acc1[p].y, m);
    }
  }
  const int w = t >> 6, lane = t & 63;
  if (lane == 0) {
#pragma unroll
    for (int r = 0; r < kLR; ++r) {
      red[w][r]       = (r & 1) ? acc0[r >> 1].y : acc0[r >> 1].x;
      red[w][kLR + r] = (r & 1) ? acc1[r >> 1].y : acc1[r >> 1].x;
    }
  }
  __syncthreads();
  if (t < 2 * kLR) {
    const int o = t >> 4, r = t & 15;
    const float s = red[0][t] + red[1][t] + red[2][t] + red[3][t];
    partL[(size_t)sl * kB * 2 + (size_t)(b0 + r) * 2 + o] = s;
  }
}

// ------------- short: conv(k=3,p=1) -> relu -> partial dot -------------
// 256 threads x 2 positions each = 512 positions; rows in packed pairs.
__device__ __forceinline__ void short_path(
    int sl, int rg, const float* __restrict__ xs, const float* __restrict__ cw,
    const float* __restrict__ cb, const float* __restrict__ lw,
    float* __restrict__ partS, float (*red)[32]) {
  const int t = threadIdx.x;
  const int b0 = rg * kSR;
  const int q = sl * 512 + 2 * t;      // first of this lane's two positions

  float wgt[8][3], bias[8];
#pragma unroll
  for (int c = 0; c < 8; ++c) {
#pragma unroll
    for (int k = 0; k < 3; ++k) wgt[c][k] = cw[c * 3 + k];
    bias[c] = cb[c];
  }

  float la0[8], la1[8], lb0[8], lb1[8];
#pragma unroll
  for (int c = 0; c < 8; ++c) {
    float2 a = *reinterpret_cast<const float2*>(lw + (size_t)c * kSW + q);
    float2 b = *reinterpret_cast<const float2*>(lw + (size_t)(8 + c) * kSW + q);
    la0[c] = a.x; la1[c] = a.y;
    lb0[c] = b.x; lb1[c] = b.y;
  }

  v2f acc0[kSR / 2], acc1[kSR / 2];
#pragma unroll
  for (int p = 0; p < kSR / 2; ++p) { acc0[p] = s2(0.f); acc1[p] = s2(0.f); }

  const bool lo = (q > 0);
  const bool hi = (q < kSW - 2);
  const float* xb = xs + (size_t)b0 * kSW + q;

#pragma unroll
  for (int p = 0; p < kSR / 2; ++p) {
    const float* x0 = xb + (size_t)(2 * p) * kSW;
    const float* x1 = xb + (size_t)(2 * p + 1) * kSW;
    float2 A0 = lo ? *reinterpret_cast<const float2*>(x0 - 2) : make_float2(0.f, 0.f);
    float2 A1 = lo ? *reinterpret_cast<const float2*>(x1 - 2) : make_float2(0.f, 0.f);
    float2 B0 = *reinterpret_cast<const float2*>(x0);
    float2 B1 = *reinterpret_cast<const float2*>(x1);
    float2 C0 = hi ? *reinterpret_cast<const float2*>(x0 + 2) : make_float2(0.f, 0.f);
    float2 C1 = hi ? *reinterpret_cast<const float2*>(x1 + 2) : make_float2(0.f, 0.f);
    const v2f W1 = {A0.y, A1.y}, W2 = {B0.x, B1.x};
    const v2f W3 = {B0.y, B1.y}, W4 = {C0.x, C1.x};
#pragma unroll
    for (int c = 0; c < 8; ++c) {
      v2f v0 = vfma(s2(wgt[c][0]), W1,
               vfma(s2(wgt[c][1]), W2,
               vfma(s2(wgt[c][2]), W3, s2(bias[c]))));
      v2f v1 = vfma(s2(wgt[c][0]), W2,
               vfma(s2(wgt[c][1]), W3,
               vfma(s2(wgt[c][2]), W4, s2(bias[c]))));
      const v2f m0 = vmax2(v0, s2(0.f));
      const v2f m1 = vmax2(v1, s2(0.f));
      acc0[p] = vfma(m1, s2(la1[c]), vfma(m0, s2(la0[c]), acc0[p]));
      acc1[p] = vfma(m1, s2(lb1[c]), vfma(m0, s2(lb0[c]), acc1[p]));
    }
  }

#pragma unroll
  for (int m = 1; m < 64; m <<= 1) {
#pragma unroll
    for (int p = 0; p < kSR / 2; ++p) {
      acc0[p].x += __shfl_xor(acc0[p].x, m);
      acc0[p].y += __shfl_xor(acc0[p].y, m);
      acc1[p].x += __shfl_xor(acc1[p].x, m);
      acc1[p].y += __shfl_xor(acc1[p].y, m);
    }
  }
  const int w = t >> 6, lane = t & 63;
  if (lane == 0) {
#pragma unroll
    for (int r = 0; r < kSR; ++r) {
      red[w][r]       = (r & 1) ? acc0[r >> 1].y : acc0[r >> 1].x;
      red[w][kSR + r] = (r & 1) ? acc1[r >> 1].y : acc1[r >> 1].x;
    }
  }
  __syncthreads();
  if (t < 2 * kSR) {
    const int o = t >> 3, r = t & 7;
    const float s = red[0][t] + red[1][t] + red[2][t] + red[3][t];
    partS[(size_t)sl * kB * 2 + (size_t)(b0 + r) * 2 + o] = s;
  }
}

// ------------- fused feature kernel: interleaved 2 long : 1 short -------------
__global__ __launch_bounds__(256, 4) void features_kernel(
    const float* __restrict__ xs, const float* __restrict__ cs_cw,
    const float* __restrict__ cs_cb, const float* __restrict__ cs_lw,
    const float* __restrict__ xl, const float* __restrict__ cl_cw,
    const float* __restrict__ cl_cb, const float* __restrict__ cl_lw,
    float* __restrict__ partS, float* __restrict__ partL) {
  __shared__ float red[4][32];
  const int bid = blockIdx.x;
  const int tri = bid / 3, rem = bid % 3;
  if (rem < 2) {
    const int li = tri * 2 + rem;          // [0, 2048)
    long_path(li >> 7, li & 127, xl, cl_cw, cl_cb, cl_lw, partL, red);
  } else {
    const int si = tri;                    // [0, 1024)
    short_path(si >> 8, si & 255, xs, cs_cw, cs_cb, cs_lw, partS, red);
  }
}

// ---------------- 4-qubit statevector circuit + final linear ----------------
template <int MASK>
__device__ __forceinline__ void apply_1q(float (&ar)[16], float (&ai)[16],
                                         float u00r, float u00i, float u01r, float u01i,
                                         float u10r, float u10i, float u11r, float u11i) {
#pragma unroll
  for (int i = 0; i < 16; ++i) {
    if (!(i & MASK)) {
      const int j = i | MASK;
      const float a0r = ar[i], a0i = ai[i];
      const float a1r = ar[j], a1i = ai[j];
      ar[i] = u00r * a0r - u00i * a0i + u01r * a1r - u01i * a1i;
      ai[i] = u00r * a0i + u00i * a0r + u01r * a1i + u01i * a1r;
      ar[j] = u10r * a0r - u10i * a0i + u11r * a1r - u11i * a1i;
      ai[j] = u10r * a0i + u10i * a0r + u11r * a1i + u11i * a1r;
    }
  }
}

template <int MASK>
__device__ __forceinline__ void apply_ry(float (&ar)[16], float (&ai)[16], float half_t) {
  float s, c;
  sincosf(half_t, &s, &c);
  apply_1q<MASK>(ar, ai, c, 0.f, -s, 0.f, s, 0.f, c, 0.f);
}

// Rot(phi, theta, omega) = RZ(omega) @ RY(theta) @ RZ(phi)
template <int MASK>
__device__ __forceinline__ void apply_rot(float (&ar)[16], float (&ai)[16],
                                          float phi, float theta, float omega) {
  float st, ct; sincosf(0.5f * theta, &st, &ct);
  float sa, ca; sincosf(0.5f * (phi + omega), &sa, &ca);
  float sm, cm; sincosf(0.5f * (phi - omega), &sm, &cm);
  apply_1q<MASK>(ar, ai,
                 ct * ca, -ct * sa,
                 -st * cm, -st * sm,
                 st * cm, -st * sm,
                 ct * ca, ct * sa);
}

template <int MC, int MT>
__device__ __forceinline__ void apply_cnot(float (&ar)[16], float (&ai)[16]) {
#pragma unroll
  for (int i = 0; i < 16; ++i) {
    if ((i & MC) && !(i & MT)) {
      const int j = i | MT;
      float t;
      t = ar[i]; ar[i] = ar[j]; ar[j] = t;
      t = ai[i]; ai[i] = ai[j]; ai[j] = t;
    }
  }
}

__global__ __launch_bounds__(64) void quantum_kernel(
    const float* __restrict__ partS, const float* __restrict__ partL,
    const float* __restrict__ cs_lb, const float* __restrict__ cl_lb,
    const float* __restrict__ rw, const float* __restrict__ fcw,
    const float* __restrict__ fcb, float* __restrict__ out) {
  const int b = blockIdx.x * 64 + threadIdx.x;
  if (b >= kB) return;

  float f0 = cs_lb[0], f1 = cs_lb[1];
#pragma unroll
  for (int sl = 0; sl < kSSL; ++sl) {
    float2 p = *reinterpret_cast<const float2*>(partS + (size_t)sl * kB * 2 + b * 2);
    f0 += p.x; f1 += p.y;
  }
  float f2 = cl_lb[0], f3 = cl_lb[1];
#pragma unroll
  for (int sl = 0; sl < kLSL; ++sl) {
    float2 p = *reinterpret_cast<const float2*>(partL + (size_t)sl * kB * 2 + b * 2);
    f2 += p.x; f3 += p.y;
  }

  float ar[16], ai[16];
#pragma unroll
  for (int i = 0; i < 16; ++i) { ar[i] = 0.f; ai[i] = 0.f; }
  ar[0] = 1.f;

  const float kHalfPi = 1.57079632679489662f;
  apply_ry<8>(ar, ai, kHalfPi * f0);
  apply_ry<4>(ar, ai, kHalfPi * f1);
  apply_ry<2>(ar, ai, kHalfPi * f2);
  apply_ry<1>(ar, ai, kHalfPi * f3);

  // layer 0, r = 1
  apply_rot<8>(ar, ai, rw[0], rw[1], rw[2]);
  apply_rot<4>(ar, ai, rw[3], rw[4], rw[5]);
  apply_rot<2>(ar, ai, rw[6], rw[7], rw[8]);
  apply_rot<1>(ar, ai, rw[9], rw[10], rw[11]);
  apply_cnot<8, 4>(ar, ai);
  apply_cnot<4, 2>(ar, ai);
  apply_cnot<2, 1>(ar, ai);
  apply_cnot<1, 8>(ar, ai);

  // layer 1, r = 2
  apply_rot<8>(ar, ai, rw[12], rw[13], rw[14]);
  apply_rot<4>(ar, ai, rw[15], rw[16], rw[17]);
  apply_rot<2>(ar, ai, rw[18], rw[19], rw[20]);
  apply_rot<1>(ar, ai, rw[21], rw[22], rw[23]);
  apply_cnot<8, 2>(ar, ai);
  apply_cnot<4, 1>(ar, ai);
  apply_cnot<2, 8>(ar, ai);
  apply_cnot<1, 4>(ar, ai);

  // layer 2, r = 3
  apply_rot<8>(ar, ai, rw[24], rw[25], rw[26]);
  apply_rot<4>(ar, ai, rw[27], rw[28], rw[29]);
  apply_rot<2>(ar, ai, rw[30], rw[31], rw[32]);
  apply_rot<1>(ar, ai, rw[33], rw[34], rw[35]);
  apply_cnot<8, 1>(ar, ai);
  apply_cnot<4, 8>(ar, ai);
  apply_cnot<2, 4>(ar, ai);
  apply_cnot<1, 2>(ar, ai);

  float z0 = 0.f, z1 = 0.f, z2 = 0.f, z3 = 0.f;
#pragma unroll
  for (int i = 0; i < 16; ++i) {
    const float p = ar[i] * ar[i] + ai[i] * ai[i];
    z0 += (i & 8) ? -p : p;
    z1 += (i & 4) ? -p : p;
    z2 += (i & 2) ? -p : p;
    z3 += (i & 1) ? -p : p;
  }
  out[b] = fcb[0] + z0 * fcw[0] + z1 * fcw[1] + z2 * fcw[2] + z3 * fcw[3];
}

extern "C" void kernel_launch(void* const* d_in, const int* in_sizes, int n_in,
                              void* d_out, int out_size, void* d_ws, size_t ws_size,
                              hipStream_t stream) {
  const float* xs     = (const float*)d_in[0];
  const float* xl     = (const float*)d_in[1];
  const float* cs_cw  = (const float*)d_in[2];
  const float* cs_cb  = (const float*)d_in[3];
  const float* cs_lw  = (const float*)d_in[4];
  const float* cs_lb  = (const float*)d_in[5];
  const float* cl_cw  = (const float*)d_in[6];
  const float* cl_cb  = (const float*)d_in[7];
  const float* cl_lw  = (const float*)d_in[8];
  const float* cl_lb  = (const float*)d_in[9];
  const float* rw     = (const float*)d_in[10];
  const float* fcw    = (const float*)d_in[11];
  const float* fcb    = (const float*)d_in[12];
  float* out   = (float*)d_out;
  float* partS = (float*)d_ws;                       // [4][kB][2]  = 64 KB
  float* partL = (float*)d_ws + kSSL * kB * 2;       // [16][kB][2] = 256 KB

  hipLaunchKernelGGL(features_kernel, dim3(kNBLK), dim3(256), 0, stream,
                     xs, cs_cw, cs_cb, cs_lw,
                     xl, cl_cw, cl_cb, cl_lw, partS, partL);
  hipLaunchKernelGGL(quantum_kernel, dim3(kB / 64), dim3(64), 0, stream,
                     partS, partL, cs_lb, cl_lb, rw, fcw, fcb, out);
}